// Round 1
// baseline (2270.873 us; speedup 1.0000x reference)
//
#include <hip/hip_runtime.h>
#include <math.h>

#define NB   4
#define NN   2048
#define DD   512
#define NOUT 512
#define NH   8
#define HDIM 64

// ---------------------------------------------------------------------------
// Tiled fp32 GEMM: C[8192,512] = A[8192,512] @ W[512,512] + bias[512]
// 64x64 tile, BK=16, 256 threads, 4x4 per thread.
// qkv_mode==1: scatter into [B,H,N,HD] layout (col tile == head, 64==HD).
// LDS pad: stride 68 floats keeps float4 alignment; worst alias is 2-way (free).
// ---------------------------------------------------------------------------
__global__ __launch_bounds__(256) void gemm512(const float* __restrict__ A,
                                               const float* __restrict__ W,
                                               const float* __restrict__ bias,
                                               float* __restrict__ C,
                                               int qkv_mode)
{
    constexpr int TS = 68;
    __shared__ float As[16 * TS];   // As[kk][i]  (transposed A tile)
    __shared__ float Bs[16 * TS];   // Bs[kk][j]

    const int t  = threadIdx.x;
    const int tx = t & 15;
    const int ty = t >> 4;
    const int jb = blockIdx.x;      // 0..7  col tile (== head in qkv mode)
    const int ib = blockIdx.y;      // 0..127 row tile

    const int arow = t >> 2;        // 0..63
    const int acol = (t & 3) * 4;   // 0,4,8,12
    const int brow = t >> 4;        // 0..15
    const int bcol = (t & 15) * 4;  // 0..60

    const float* Ap = A + (size_t)(ib * 64 + arow) * DD + acol;
    const float* Wp = W + (size_t)brow * NOUT + jb * 64 + bcol;

    float acc[4][4];
#pragma unroll
    for (int a = 0; a < 4; ++a)
#pragma unroll
        for (int b = 0; b < 4; ++b) acc[a][b] = 0.f;

    for (int kt = 0; kt < DD / 16; ++kt) {
        float4 a4 = *(const float4*)(Ap + kt * 16);
        float4 b4 = *(const float4*)(Wp + (size_t)kt * 16 * NOUT);
        __syncthreads();
        As[(acol + 0) * TS + arow] = a4.x;
        As[(acol + 1) * TS + arow] = a4.y;
        As[(acol + 2) * TS + arow] = a4.z;
        As[(acol + 3) * TS + arow] = a4.w;
        *(float4*)(&Bs[brow * TS + bcol]) = b4;
        __syncthreads();
#pragma unroll
        for (int kk = 0; kk < 16; ++kk) {
            float4 av = *(const float4*)(&As[kk * TS + ty * 4]);
            float4 bv = *(const float4*)(&Bs[kk * TS + tx * 4]);
            float aa[4] = {av.x, av.y, av.z, av.w};
            float bb[4] = {bv.x, bv.y, bv.z, bv.w};
#pragma unroll
            for (int a = 0; a < 4; ++a)
#pragma unroll
                for (int b = 0; b < 4; ++b)
                    acc[a][b] = fmaf(aa[a], bb[b], acc[a][b]);
        }
    }

    const float4 bi = *(const float4*)(bias + jb * 64 + tx * 4);
    const float bias4[4] = {bi.x, bi.y, bi.z, bi.w};
#pragma unroll
    for (int a = 0; a < 4; ++a) {
        const int row = ib * 64 + ty * 4 + a;   // 0..8191 = b*N + n
        float4 o;
        o.x = acc[a][0] + bias4[0];
        o.y = acc[a][1] + bias4[1];
        o.z = acc[a][2] + bias4[2];
        o.w = acc[a][3] + bias4[3];
        if (qkv_mode) {
            const int bb = row >> 11;           // / N
            const int n  = row & (NN - 1);
            float* dst = C + ((size_t)(bb * NH + jb) * NN + n) * HDIM + tx * 4;
            *(float4*)dst = o;
        } else {
            *(float4*)(C + (size_t)row * NOUT + jb * 64 + tx * 4) = o;
        }
    }
}

// ---------------------------------------------------------------------------
// Flash-style masked attention. One block per (b, h, 64-query tile).
// K/V staged in LDS 64 keys at a time; online softmax; O in registers.
// ---------------------------------------------------------------------------
__global__ __launch_bounds__(256) void attn64(const float* __restrict__ qg,
                                              const float* __restrict__ kg,
                                              const float* __restrict__ vg,
                                              const int*   __restrict__ adj,
                                              float* __restrict__ ao)
{
    constexpr int TS = 68;
    __shared__ float Qs[64 * TS];
    __shared__ float Ks[64 * TS];
    __shared__ float Vs[64 * TS];
    __shared__ float Ss[64 * TS];
    __shared__ float m_s[64], l_s[64], alpha_s[64];
    __shared__ float redm[64][4], redl[64][4];

    const int t  = threadIdx.x;
    const int qt = blockIdx.x;   // 0..31
    const int h  = blockIdx.y;   // 0..7
    const int b  = blockIdx.z;   // 0..3
    const int bh = b * NH + h;
    const int q0 = qt * 64;
    const float scale = 0.125f;  // HD^-0.5

    // ---- load Q tile 64x64 ----
    const float* qbase = qg + (size_t)bh * NN * HDIM + (size_t)q0 * HDIM;
#pragma unroll
    for (int p = 0; p < 4; ++p) {
        const int f4  = p * 256 + t;      // 0..1023 float4 index
        const int row = f4 >> 4;
        const int col = (f4 & 15) * 4;
        *(float4*)(&Qs[row * TS + col]) = *(const float4*)(qbase + row * HDIM + col);
    }
    if (t < 64) { m_s[t] = -1e30f; l_s[t] = 0.f; }

    float O[16];
#pragma unroll
    for (int u = 0; u < 16; ++u) O[u] = 0.f;

    const int ty = t >> 4, tx = t & 15;
    const int i0 = ty * 4, j0 = tx * 4;      // score mapping
    const int r  = t >> 2, c4 = t & 3;       // softmax mapping
    const int pv_i = t >> 2, dg = t & 3;     // PV mapping
    const int d0 = dg * 16;

    const float* kbase = kg + (size_t)bh * NN * HDIM;
    const float* vbase = vg + (size_t)bh * NN * HDIM;

    for (int kt = 0; kt < NN / 64; ++kt) {
        const int k0 = kt * 64;
        __syncthreads();   // prior PV done; safe to overwrite Ks/Vs (also covers Q/m/l init)
        // ---- load K,V tiles ----
#pragma unroll
        for (int p = 0; p < 4; ++p) {
            const int f4  = p * 256 + t;
            const int row = f4 >> 4;
            const int col = (f4 & 15) * 4;
            float4 k4 = *(const float4*)(kbase + (size_t)(k0 + row) * HDIM + col);
            float4 v4 = *(const float4*)(vbase + (size_t)(k0 + row) * HDIM + col);
            *(float4*)(&Ks[row * TS + col]) = k4;
            *(float4*)(&Vs[row * TS + col]) = v4;
        }
        __syncthreads();

        // ---- scores: 4x4 per thread ----
        float acc[4][4];
#pragma unroll
        for (int a = 0; a < 4; ++a)
#pragma unroll
            for (int bb = 0; bb < 4; ++bb) acc[a][bb] = 0.f;
#pragma unroll
        for (int kk = 0; kk < 16; ++kk) {
            float4 qa[4], kb[4];
#pragma unroll
            for (int a = 0; a < 4; ++a)
                qa[a] = *(const float4*)(&Qs[(i0 + a) * TS + kk * 4]);
#pragma unroll
            for (int bb = 0; bb < 4; ++bb)
                kb[bb] = *(const float4*)(&Ks[(j0 + bb) * TS + kk * 4]);
#pragma unroll
            for (int a = 0; a < 4; ++a)
#pragma unroll
                for (int bb = 0; bb < 4; ++bb) {
                    acc[a][bb] = fmaf(qa[a].x, kb[bb].x, acc[a][bb]);
                    acc[a][bb] = fmaf(qa[a].y, kb[bb].y, acc[a][bb]);
                    acc[a][bb] = fmaf(qa[a].z, kb[bb].z, acc[a][bb]);
                    acc[a][bb] = fmaf(qa[a].w, kb[bb].w, acc[a][bb]);
                }
        }
        // ---- mask + scale, write S tile ----
#pragma unroll
        for (int a = 0; a < 4; ++a) {
            const int4 ad = *(const int4*)(adj + (size_t)(q0 + i0 + a) * NN + k0 + j0);
            float4 sv;
            sv.x = ad.x ? acc[a][0] * scale : -1e9f;
            sv.y = ad.y ? acc[a][1] * scale : -1e9f;
            sv.z = ad.z ? acc[a][2] * scale : -1e9f;
            sv.w = ad.w ? acc[a][3] * scale : -1e9f;
            *(float4*)(&Ss[(i0 + a) * TS + j0]) = sv;
        }
        __syncthreads();

        // ---- online softmax: 4 threads per row ----
        float lmax = -1e30f;
#pragma unroll
        for (int u = 0; u < 16; ++u)
            lmax = fmaxf(lmax, Ss[r * TS + c4 * 16 + u]);
        redm[r][c4] = lmax;
        __syncthreads();
        const float mold = m_s[r];
        float mnew = fmaxf(fmaxf(redm[r][0], redm[r][1]),
                           fmaxf(redm[r][2], redm[r][3]));
        mnew = fmaxf(mold, mnew);
        float lsum = 0.f;
#pragma unroll
        for (int u = 0; u < 16; ++u) {
            const float p = __expf(Ss[r * TS + c4 * 16 + u] - mnew);
            Ss[r * TS + c4 * 16 + u] = p;
            lsum += p;
        }
        redl[r][c4] = lsum;
        __syncthreads();
        if (c4 == 0) {
            const float al = __expf(mold - mnew);
            alpha_s[r] = al;
            l_s[r] = l_s[r] * al + redl[r][0] + redl[r][1] + redl[r][2] + redl[r][3];
            m_s[r] = mnew;
        }
        __syncthreads();

        // ---- PV: O[i][d0..d0+15] += P[i][j] * V[j][...] ----
        const float al = alpha_s[pv_i];
#pragma unroll
        for (int u = 0; u < 16; ++u) O[u] *= al;
#pragma unroll 8
        for (int j = 0; j < 64; ++j) {
            const float p  = Ss[pv_i * TS + j];
            const float4 v0 = *(const float4*)(&Vs[j * TS + d0 + 0]);
            const float4 v1 = *(const float4*)(&Vs[j * TS + d0 + 4]);
            const float4 v2 = *(const float4*)(&Vs[j * TS + d0 + 8]);
            const float4 v3 = *(const float4*)(&Vs[j * TS + d0 + 12]);
            O[0]  = fmaf(p, v0.x, O[0]);  O[1]  = fmaf(p, v0.y, O[1]);
            O[2]  = fmaf(p, v0.z, O[2]);  O[3]  = fmaf(p, v0.w, O[3]);
            O[4]  = fmaf(p, v1.x, O[4]);  O[5]  = fmaf(p, v1.y, O[5]);
            O[6]  = fmaf(p, v1.z, O[6]);  O[7]  = fmaf(p, v1.w, O[7]);
            O[8]  = fmaf(p, v2.x, O[8]);  O[9]  = fmaf(p, v2.y, O[9]);
            O[10] = fmaf(p, v2.z, O[10]); O[11] = fmaf(p, v2.w, O[11]);
            O[12] = fmaf(p, v3.x, O[12]); O[13] = fmaf(p, v3.y, O[13]);
            O[14] = fmaf(p, v3.w == v3.w ? v3.z : v3.z, O[14]); // v3.z
            O[15] = fmaf(p, v3.w, O[15]);
        }
    }

    // ---- epilogue: normalize and write [B,N,OUT] layout ----
    const float inv = 1.f / l_s[pv_i];
#pragma unroll
    for (int u = 0; u < 16; ++u) O[u] *= inv;
    float* dst = ao + ((size_t)(b * NN + q0 + pv_i) * NOUT) + h * HDIM + d0;
    *(float4*)(dst + 0)  = make_float4(O[0],  O[1],  O[2],  O[3]);
    *(float4*)(dst + 4)  = make_float4(O[4],  O[5],  O[6],  O[7]);
    *(float4*)(dst + 8)  = make_float4(O[8],  O[9],  O[10], O[11]);
    *(float4*)(dst + 12) = make_float4(O[12], O[13], O[14], O[15]);
}

// ---------------------------------------------------------------------------
extern "C" void kernel_launch(void* const* d_in, const int* in_sizes, int n_in,
                              void* d_out, int out_size, void* d_ws, size_t ws_size,
                              hipStream_t stream)
{
    const float* x   = (const float*)d_in[0];
    const int*   adj = (const int*)  d_in[1];
    const float* Wq  = (const float*)d_in[2];
    const float* bq  = (const float*)d_in[3];
    const float* Wk  = (const float*)d_in[4];
    const float* bk  = (const float*)d_in[5];
    const float* Wv  = (const float*)d_in[6];
    const float* bv  = (const float*)d_in[7];
    const float* Wo  = (const float*)d_in[8];
    const float* bo  = (const float*)d_in[9];
    float* out = (float*)d_out;

    // workspace: q,k,v in [B,H,N,HD]; attn_out in [B,N,OUT]  (4x16MB = 64MB)
    float* q   = (float*)d_ws;
    float* kbf = q   + (size_t)NB * NH * NN * HDIM;
    float* vbf = kbf + (size_t)NB * NH * NN * HDIM;
    float* ao  = vbf + (size_t)NB * NH * NN * HDIM;

    dim3 ggrid(NOUT / 64, (NB * NN) / 64);   // (8, 128)
    gemm512<<<ggrid, 256, 0, stream>>>(x, Wq, bq, q,   1);
    gemm512<<<ggrid, 256, 0, stream>>>(x, Wk, bk, kbf, 1);
    gemm512<<<ggrid, 256, 0, stream>>>(x, Wv, bv, vbf, 1);

    attn64<<<dim3(NN / 64, NH, NB), 256, 0, stream>>>(q, kbf, vbf, adj, ao);

    gemm512<<<ggrid, 256, 0, stream>>>(ao, Wo, bo, out, 0);
}

// Round 2
// 467.803 us; speedup vs baseline: 4.8543x; 4.8543x over previous
//
#include <hip/hip_runtime.h>
#include <math.h>

#define NB   4
#define NN   2048
#define DD   512
#define NOUT 512
#define NH   8
#define HDIM 64

typedef __attribute__((ext_vector_type(8))) short bf16x8;
typedef __attribute__((ext_vector_type(4))) float f32x4;
#define MFMA16(a, b, c) __builtin_amdgcn_mfma_f32_16x16x32_bf16(a, b, c, 0, 0, 0)

__device__ inline unsigned short f2bf(float f) {
    unsigned int u = __float_as_uint(f);
    u += 0x7fffu + ((u >> 16) & 1u);   // round-to-nearest-even
    return (unsigned short)(u >> 16);
}

// ---------------------------------------------------------------------------
// Tiled fp32 GEMM: C[8192,512] = A[8192,512] @ W[512,512] + bias[512]
// qkv_mode==1: write bf16 into [B,H,N,HD] (col tile == head since 64==HD).
// qkv_mode==0: write fp32 [8192,512].
// ---------------------------------------------------------------------------
__global__ __launch_bounds__(256) void gemm512(const float* __restrict__ A,
                                               const float* __restrict__ W,
                                               const float* __restrict__ bias,
                                               float* __restrict__ Cf,
                                               unsigned short* __restrict__ Cb,
                                               int qkv_mode)
{
    constexpr int TS = 68;
    __shared__ float As[16 * TS];   // As[kk][i]
    __shared__ float Bs[16 * TS];   // Bs[kk][j]

    const int t  = threadIdx.x;
    const int tx = t & 15;
    const int ty = t >> 4;
    const int jb = blockIdx.x;
    const int ib = blockIdx.y;

    const int arow = t >> 2;
    const int acol = (t & 3) * 4;
    const int brow = t >> 4;
    const int bcol = (t & 15) * 4;

    const float* Ap = A + (size_t)(ib * 64 + arow) * DD + acol;
    const float* Wp = W + (size_t)brow * NOUT + jb * 64 + bcol;

    float acc[4][4];
#pragma unroll
    for (int a = 0; a < 4; ++a)
#pragma unroll
        for (int b = 0; b < 4; ++b) acc[a][b] = 0.f;

    for (int kt = 0; kt < DD / 16; ++kt) {
        float4 a4 = *(const float4*)(Ap + kt * 16);
        float4 b4 = *(const float4*)(Wp + (size_t)kt * 16 * NOUT);
        __syncthreads();
        As[(acol + 0) * TS + arow] = a4.x;
        As[(acol + 1) * TS + arow] = a4.y;
        As[(acol + 2) * TS + arow] = a4.z;
        As[(acol + 3) * TS + arow] = a4.w;
        *(float4*)(&Bs[brow * TS + bcol]) = b4;
        __syncthreads();
#pragma unroll
        for (int kk = 0; kk < 16; ++kk) {
            float4 av = *(const float4*)(&As[kk * TS + ty * 4]);
            float4 bv = *(const float4*)(&Bs[kk * TS + tx * 4]);
            float aa[4] = {av.x, av.y, av.z, av.w};
            float bb[4] = {bv.x, bv.y, bv.z, bv.w};
#pragma unroll
            for (int a = 0; a < 4; ++a)
#pragma unroll
                for (int b = 0; b < 4; ++b)
                    acc[a][b] = fmaf(aa[a], bb[b], acc[a][b]);
        }
    }

    const float4 bi = *(const float4*)(bias + jb * 64 + tx * 4);
    const float bias4[4] = {bi.x, bi.y, bi.z, bi.w};
#pragma unroll
    for (int a = 0; a < 4; ++a) {
        const int row = ib * 64 + ty * 4 + a;
        float4 o;
        o.x = acc[a][0] + bias4[0];
        o.y = acc[a][1] + bias4[1];
        o.z = acc[a][2] + bias4[2];
        o.w = acc[a][3] + bias4[3];
        if (qkv_mode) {
            const int bb = row >> 11;
            const int n  = row & (NN - 1);
            unsigned short* dst = Cb + ((size_t)(bb * NH + jb) * NN + n) * HDIM + tx * 4;
            ushort4 u;
            u.x = f2bf(o.x); u.y = f2bf(o.y); u.z = f2bf(o.z); u.w = f2bf(o.w);
            *(ushort4*)dst = u;
        } else {
            *(float4*)(Cf + (size_t)row * NOUT + jb * 64 + tx * 4) = o;
        }
    }
}

// ---------------------------------------------------------------------------
// adj [2048,2048] int -> bitmask [2048 rows][32 u64 words]
// one wave per (row, word)
// ---------------------------------------------------------------------------
__global__ __launch_bounds__(256) void pack_adj(const int* __restrict__ adj,
                                                unsigned long long* __restrict__ bits)
{
    const int gw   = blockIdx.x * 4 + (threadIdx.x >> 6);
    const int lane = threadIdx.x & 63;
    const int row  = gw >> 5;
    const int word = gw & 31;
    const unsigned long long m = __ballot(adj[(size_t)row * NN + word * 64 + lane] != 0);
    if (lane == 0) bits[(size_t)row * 32 + word] = m;
}

// ---------------------------------------------------------------------------
// MFMA flash attention. Block = (b,h,64 queries), 4 waves (16 q each).
// Per 64-key tile: Ks row-major bf16, Vt transposed bf16 (rows padded to 72
// shorts = 144 B -> strided frag reads are 2-way bank aliases = free).
// QK^T: 8 mfma_f32_16x16x32_bf16 / wave; online softmax in C-layout via
// shfl_xor over 16-lane groups; P round-trips LDS (per-wave region, no
// barrier) into A-layout; PV: 8 MFMAs. Mask via packed bit words.
// ---------------------------------------------------------------------------
__global__ __launch_bounds__(256) void attn_mfma(
    const unsigned short* __restrict__ qg,
    const unsigned short* __restrict__ kg,
    const unsigned short* __restrict__ vg,
    const unsigned long long* __restrict__ bitadj,
    float* __restrict__ ao)
{
    constexpr int RS = 72;  // LDS row stride in shorts (144 B)
    __shared__ unsigned short Qs[64 * RS];
    __shared__ unsigned short Ks[64 * RS];
    __shared__ unsigned short Vt[64 * RS];      // Vt[d][key]
    __shared__ unsigned short Ps[4][16 * RS];   // per-wave P scratch

    const int t    = threadIdx.x;
    const int wave = t >> 6;
    const int lane = t & 63;
    const int quad = lane >> 4;
    const int l16  = lane & 15;

    const int qt = blockIdx.x, h = blockIdx.y, b = blockIdx.z;
    const int bh = b * NH + h;
    const int q0 = qt * 64;
    const float scale = 0.125f;

    const unsigned short* qbase = qg + (size_t)bh * NN * HDIM + (size_t)q0 * HDIM;
    const unsigned short* kbase = kg + (size_t)bh * NN * HDIM;
    const unsigned short* vbase = vg + (size_t)bh * NN * HDIM;

    // ---- stage Q tile (64 q x 64 d) ----
    {
        const int row = t >> 2, col = (t & 3) * 16;
        const unsigned short* src = qbase + row * HDIM + col;
        *(bf16x8*)&Qs[row * RS + col]     = *(const bf16x8*)src;
        *(bf16x8*)&Qs[row * RS + col + 8] = *(const bf16x8*)(src + 8);
    }
    __syncthreads();

    // Q A-frags: m=l16 (query), k = quad*8+j (+32*chunk)
    bf16x8 aQ0 = *(const bf16x8*)&Qs[(wave * 16 + l16) * RS + quad * 8];
    bf16x8 aQ1 = *(const bf16x8*)&Qs[(wave * 16 + l16) * RS + quad * 8 + 32];

    const unsigned long long* bitrow =
        bitadj + (size_t)(q0 + wave * 16 + quad * 4) * 32;

    f32x4 O[4];
#pragma unroll
    for (int dt = 0; dt < 4; ++dt) O[dt] = (f32x4){0.f, 0.f, 0.f, 0.f};
    float m_r[4] = {-1e30f, -1e30f, -1e30f, -1e30f};
    float l_r[4] = {0.f, 0.f, 0.f, 0.f};

    for (int kt = 0; kt < NN / 64; ++kt) {
        const int k0 = kt * 64;
        __syncthreads();   // previous tile's PV reads done

        // ---- stage K (row-major) ----
        {
            const int row = t >> 2, col = (t & 3) * 16;
            const unsigned short* src = kbase + (size_t)(k0 + row) * HDIM + col;
            *(bf16x8*)&Ks[row * RS + col]     = *(const bf16x8*)src;
            *(bf16x8*)&Ks[row * RS + col + 8] = *(const bf16x8*)(src + 8);
        }
        // ---- stage V transposed: Vt[d][key] ----
        {
            const int key = lane, d0 = wave * 16;
            const unsigned short* src = vbase + (size_t)(k0 + key) * HDIM + d0;
            bf16x8 v0 = *(const bf16x8*)src;
            bf16x8 v1 = *(const bf16x8*)(src + 8);
#pragma unroll
            for (int j = 0; j < 8; ++j) Vt[(d0 + j) * RS + key]     = ((unsigned short*)&v0)[j];
#pragma unroll
            for (int j = 0; j < 8; ++j) Vt[(d0 + 8 + j) * RS + key] = ((unsigned short*)&v1)[j];
        }
        __syncthreads();

        // ---- QK^T: scores for 16 q x 64 k per wave ----
        f32x4 sc[4];
#pragma unroll
        for (int nt = 0; nt < 4; ++nt) {
            bf16x8 b0 = *(const bf16x8*)&Ks[(nt * 16 + l16) * RS + quad * 8];
            bf16x8 b1 = *(const bf16x8*)&Ks[(nt * 16 + l16) * RS + quad * 8 + 32];
            f32x4 c = (f32x4){0.f, 0.f, 0.f, 0.f};
            c = MFMA16(aQ0, b0, c);
            c = MFMA16(aQ1, b1, c);
            sc[nt] = c;
        }

        // ---- mask + scale (C layout: row=quad*4+reg, col=nt*16+l16) ----
        unsigned long long mreg[4];
#pragma unroll
        for (int r = 0; r < 4; ++r) mreg[r] = bitrow[r * 32 + kt];

        float s[4][4];
#pragma unroll
        for (int nt = 0; nt < 4; ++nt)
#pragma unroll
            for (int r = 0; r < 4; ++r) {
                const bool keep = (mreg[r] >> (nt * 16 + l16)) & 1ull;
                s[nt][r] = keep ? sc[nt][r] * scale : -1e9f;
            }

        // ---- online softmax ----
        float mnew[4], alpha[4];
#pragma unroll
        for (int r = 0; r < 4; ++r) {
            float rm = fmaxf(fmaxf(s[0][r], s[1][r]), fmaxf(s[2][r], s[3][r]));
            rm = fmaxf(rm, __shfl_xor(rm, 1));
            rm = fmaxf(rm, __shfl_xor(rm, 2));
            rm = fmaxf(rm, __shfl_xor(rm, 4));
            rm = fmaxf(rm, __shfl_xor(rm, 8));
            mnew[r]  = fmaxf(m_r[r], rm);
            alpha[r] = __expf(m_r[r] - mnew[r]);
            m_r[r]   = mnew[r];
        }
        float rs[4] = {0.f, 0.f, 0.f, 0.f};
#pragma unroll
        for (int nt = 0; nt < 4; ++nt)
#pragma unroll
            for (int r = 0; r < 4; ++r) {
                const float p = __expf(s[nt][r] - mnew[r]);
                s[nt][r] = p;
                rs[r] += p;
            }
#pragma unroll
        for (int r = 0; r < 4; ++r) {
            rs[r] += __shfl_xor(rs[r], 1);
            rs[r] += __shfl_xor(rs[r], 2);
            rs[r] += __shfl_xor(rs[r], 4);
            rs[r] += __shfl_xor(rs[r], 8);
            l_r[r] = l_r[r] * alpha[r] + rs[r];
        }

        // ---- P (bf16) -> per-wave LDS, C-layout scatter ----
#pragma unroll
        for (int nt = 0; nt < 4; ++nt)
#pragma unroll
            for (int r = 0; r < 4; ++r)
                Ps[wave][(quad * 4 + r) * RS + nt * 16 + l16] = f2bf(s[nt][r]);
        // same-wave write->read: compiler inserts lgkmcnt wait, no barrier

        // ---- P A-frags + PV ----
        bf16x8 aP0 = *(const bf16x8*)&Ps[wave][l16 * RS + quad * 8];
        bf16x8 aP1 = *(const bf16x8*)&Ps[wave][l16 * RS + quad * 8 + 32];
#pragma unroll
        for (int dt = 0; dt < 4; ++dt) {
#pragma unroll
            for (int r = 0; r < 4; ++r) O[dt][r] *= alpha[r];
            bf16x8 b0 = *(const bf16x8*)&Vt[(dt * 16 + l16) * RS + quad * 8];
            bf16x8 b1 = *(const bf16x8*)&Vt[(dt * 16 + l16) * RS + quad * 8 + 32];
            O[dt] = MFMA16(aP0, b0, O[dt]);
            O[dt] = MFMA16(aP1, b1, O[dt]);
        }
    }

    // ---- epilogue: normalize, write [B,N,OUT] fp32 ----
    float inv[4];
#pragma unroll
    for (int r = 0; r < 4; ++r) inv[r] = 1.f / l_r[r];
#pragma unroll
    for (int dt = 0; dt < 4; ++dt)
#pragma unroll
        for (int r = 0; r < 4; ++r) {
            const int q = q0 + wave * 16 + quad * 4 + r;
            ao[((size_t)(b * NN + q)) * NOUT + h * HDIM + dt * 16 + l16] =
                O[dt][r] * inv[r];
        }
}

// ---------------------------------------------------------------------------
extern "C" void kernel_launch(void* const* d_in, const int* in_sizes, int n_in,
                              void* d_out, int out_size, void* d_ws, size_t ws_size,
                              hipStream_t stream)
{
    const float* x   = (const float*)d_in[0];
    const int*   adj = (const int*)  d_in[1];
    const float* Wq  = (const float*)d_in[2];
    const float* bq  = (const float*)d_in[3];
    const float* Wk  = (const float*)d_in[4];
    const float* bk  = (const float*)d_in[5];
    const float* Wv  = (const float*)d_in[6];
    const float* bv  = (const float*)d_in[7];
    const float* Wo  = (const float*)d_in[8];
    const float* bo  = (const float*)d_in[9];
    float* out = (float*)d_out;

    const size_t qkv_elems = (size_t)NB * NH * NN * HDIM;   // 4,194,304
    unsigned short* q  = (unsigned short*)d_ws;
    unsigned short* kb = q  + qkv_elems;
    unsigned short* vb = kb + qkv_elems;
    float* ao = (float*)(vb + qkv_elems);
    unsigned long long* bits = (unsigned long long*)(ao + (size_t)NB * NN * NOUT);

    pack_adj<<<dim3(NN * 32 / 4), 256, 0, stream>>>(adj, bits);

    dim3 ggrid(NOUT / 64, (NB * NN) / 64);
    gemm512<<<ggrid, 256, 0, stream>>>(x, Wq, bq, nullptr, q,  1);
    gemm512<<<ggrid, 256, 0, stream>>>(x, Wk, bk, nullptr, kb, 1);
    gemm512<<<ggrid, 256, 0, stream>>>(x, Wv, bv, nullptr, vb, 1);

    attn_mfma<<<dim3(NN / 64, NH, NB), 256, 0, stream>>>(q, kb, vb, bits, ao);

    gemm512<<<ggrid, 256, 0, stream>>>(ao, Wo, bo, out, nullptr, 0);
}

// Round 3
// 324.225 us; speedup vs baseline: 7.0040x; 1.4428x over previous
//
#include <hip/hip_runtime.h>
#include <math.h>

#define NB   4
#define NN   2048
#define DD   512
#define NOUT 512
#define NH   8
#define HDIM 64

typedef __attribute__((ext_vector_type(8))) short bf16x8;
typedef __attribute__((ext_vector_type(4))) float f32x4;
#define MFMA16(a, b, c) __builtin_amdgcn_mfma_f32_16x16x32_bf16(a, b, c, 0, 0, 0)

typedef const __attribute__((address_space(1))) unsigned int* gas_ptr;
typedef __attribute__((address_space(3))) unsigned int* las_ptr;

__device__ inline unsigned short f2bf(float f) {
    unsigned int u = __float_as_uint(f);
    u += 0x7fffu + ((u >> 16) & 1u);   // RNE
    return (unsigned short)(u >> 16);
}

// ---------------------------------------------------------------------------
// x fp32 [4M] -> bf16
// ---------------------------------------------------------------------------
__global__ __launch_bounds__(256) void convx(const float* __restrict__ x,
                                             unsigned short* __restrict__ xb)
{
    const int i = (blockIdx.x * 256 + threadIdx.x) * 4;
    float4 v = *(const float4*)(x + i);
    ushort4 u;
    u.x = f2bf(v.x); u.y = f2bf(v.y); u.z = f2bf(v.z); u.w = f2bf(v.w);
    *(ushort4*)(xb + i) = u;
}

// ---------------------------------------------------------------------------
// W [512 k][512 n] fp32 -> Wt [512 n][512 k] bf16   (4 matrices via blockIdx.z)
// ---------------------------------------------------------------------------
__global__ __launch_bounds__(256) void transW(
    const float* __restrict__ W0, const float* __restrict__ W1,
    const float* __restrict__ W2, const float* __restrict__ W3,
    unsigned short* __restrict__ T0, unsigned short* __restrict__ T1,
    unsigned short* __restrict__ T2, unsigned short* __restrict__ T3)
{
    __shared__ float tile[64][65];
    const float* W; unsigned short* T;
    switch (blockIdx.z) {
        case 0:  W = W0; T = T0; break;
        case 1:  W = W1; T = T1; break;
        case 2:  W = W2; T = T2; break;
        default: W = W3; T = T3; break;
    }
    const int t = threadIdx.x;
    const int k0 = blockIdx.x * 64, n0 = blockIdx.y * 64;
    const int r = t >> 6, c = t & 63;
#pragma unroll
    for (int rep = 0; rep < 16; ++rep) {
        const int row = rep * 4 + r;
        tile[row][c] = W[(size_t)(k0 + row) * NOUT + n0 + c];
    }
    __syncthreads();
#pragma unroll
    for (int rep = 0; rep < 16; ++rep) {
        const int row = rep * 4 + r;          // n index
        T[(size_t)(n0 + row) * DD + k0 + c] = f2bf(tile[c][row]);
    }
}

// ---------------------------------------------------------------------------
// adj -> bitmask [2048][32] u64
// ---------------------------------------------------------------------------
__global__ __launch_bounds__(256) void pack_adj(const int* __restrict__ adj,
                                                unsigned long long* __restrict__ bits)
{
    const int gw   = blockIdx.x * 4 + (threadIdx.x >> 6);
    const int lane = threadIdx.x & 63;
    const int row  = gw >> 5;
    const int word = gw & 31;
    const unsigned long long m = __ballot(adj[(size_t)row * NN + word * 64 + lane] != 0);
    if (lane == 0) bits[(size_t)row * 32 + word] = m;
}

// ---------------------------------------------------------------------------
// bf16 MFMA GEMM: C[8192,512] = A[8192,512] @ W  (Wt = W^T bf16 [n][k])
// 128x128 tile, BK=32, 4 waves (64x64 each), global_load_lds width 16.
// LDS layout [kc][row][8 bf16] — granule order matches lane*16 contiguity.
// mode 0: bf16 out [B,H,N,64]; mode 1: bf16 V^T [B,H,64,N]; mode 2: fp32 [8192,512]
// ---------------------------------------------------------------------------
__global__ __launch_bounds__(256) void gemm_mfma(
    const unsigned short* __restrict__ A,
    const unsigned short* __restrict__ Wt,
    const float* __restrict__ bias,
    void* __restrict__ Cout,
    int mode)
{
    __shared__ unsigned short As[4 * 128 * 8];   // [kc][m][8]
    __shared__ unsigned short Ws[4 * 128 * 8];   // [kc][n][8]

    const int t = threadIdx.x, wave = t >> 6, lane = t & 63;
    const int quad = lane >> 4, l16 = lane & 15;
    const int n0 = blockIdx.x * 128, m0 = blockIdx.y * 128;

    // staging assignment: wave issues A chunks wave*2, wave*2+1 and same for W
    const int ca0 = wave * 2, ca1 = wave * 2 + 1;
    const int kcA0 = ca0 >> 1, hfA0 = ca0 & 1;
    const int kcA1 = ca1 >> 1, hfA1 = ca1 & 1;

    const unsigned short* gA0 = A  + (size_t)(m0 + hfA0 * 64 + lane) * DD + kcA0 * 8;
    const unsigned short* gA1 = A  + (size_t)(m0 + hfA1 * 64 + lane) * DD + kcA1 * 8;
    const unsigned short* gW0 = Wt + (size_t)(n0 + hfA0 * 64 + lane) * DD + kcA0 * 8;
    const unsigned short* gW1 = Wt + (size_t)(n0 + hfA1 * 64 + lane) * DD + kcA1 * 8;

    unsigned short* lA0 = As + (kcA0 * 128 + hfA0 * 64) * 8;
    unsigned short* lA1 = As + (kcA1 * 128 + hfA1 * 64) * 8;
    unsigned short* lW0 = Ws + (kcA0 * 128 + hfA0 * 64) * 8;
    unsigned short* lW1 = Ws + (kcA1 * 128 + hfA1 * 64) * 8;

    const int wm = (wave & 1) * 64, wn = (wave >> 1) * 64;

    f32x4 acc[4][4];
#pragma unroll
    for (int mt = 0; mt < 4; ++mt)
#pragma unroll
        for (int nt = 0; nt < 4; ++nt) acc[mt][nt] = (f32x4){0.f, 0.f, 0.f, 0.f};

    for (int kt = 0; kt < DD / 32; ++kt) {
        __syncthreads();   // previous iter's frag reads complete
        __builtin_amdgcn_global_load_lds((gas_ptr)(gA0 + kt * 32), (las_ptr)lA0, 16, 0, 0);
        __builtin_amdgcn_global_load_lds((gas_ptr)(gA1 + kt * 32), (las_ptr)lA1, 16, 0, 0);
        __builtin_amdgcn_global_load_lds((gas_ptr)(gW0 + kt * 32), (las_ptr)lW0, 16, 0, 0);
        __builtin_amdgcn_global_load_lds((gas_ptr)(gW1 + kt * 32), (las_ptr)lW1, 16, 0, 0);
        __syncthreads();   // drains vmcnt before barrier

        bf16x8 aF[4], bF[4];
#pragma unroll
        for (int mt = 0; mt < 4; ++mt)
            aF[mt] = *(const bf16x8*)&As[(quad * 128 + wm + mt * 16 + l16) * 8];
#pragma unroll
        for (int nt = 0; nt < 4; ++nt)
            bF[nt] = *(const bf16x8*)&Ws[(quad * 128 + wn + nt * 16 + l16) * 8];
#pragma unroll
        for (int mt = 0; mt < 4; ++mt)
#pragma unroll
            for (int nt = 0; nt < 4; ++nt)
                acc[mt][nt] = MFMA16(aF[mt], bF[nt], acc[mt][nt]);
    }

    float bias4[4];
#pragma unroll
    for (int nt = 0; nt < 4; ++nt) bias4[nt] = bias[n0 + wn + nt * 16 + l16];

#pragma unroll
    for (int mt = 0; mt < 4; ++mt) {
#pragma unroll
        for (int nt = 0; nt < 4; ++nt) {
            const int col = n0 + wn + nt * 16 + l16;
#pragma unroll
            for (int r = 0; r < 4; ++r) {
                const int row = m0 + wm + mt * 16 + quad * 4 + r;
                const float val = acc[mt][nt][r] + bias4[nt];
                if (mode == 0) {
                    const int bb = row >> 11, n = row & (NN - 1);
                    const int h = col >> 6, d = col & 63;
                    ((unsigned short*)Cout)[((size_t)(bb * NH + h) * NN + n) * HDIM + d] = f2bf(val);
                } else if (mode == 1) {
                    const int bb = row >> 11, n = row & (NN - 1);
                    const int h = col >> 6, d = col & 63;
                    ((unsigned short*)Cout)[((size_t)(bb * NH + h) * HDIM + d) * NN + n] = f2bf(val);
                } else {
                    ((float*)Cout)[(size_t)row * NOUT + col] = val;
                }
            }
        }
    }
}

// ---------------------------------------------------------------------------
// MFMA flash attention. V^T comes pre-transposed from global ([B,H,64,N]).
// Logits pre-scaled by HD^-0.5 * log2(e); exp2f throughout.
// ao written as bf16 [B,N,OUT].
// ---------------------------------------------------------------------------
__global__ __launch_bounds__(256) void attn_mfma(
    const unsigned short* __restrict__ qg,
    const unsigned short* __restrict__ kg,
    const unsigned short* __restrict__ vt,
    const unsigned long long* __restrict__ bitadj,
    unsigned short* __restrict__ ao)
{
    constexpr int RS = 72;
    __shared__ unsigned short Qs[64 * RS];
    __shared__ unsigned short Ks[64 * RS];
    __shared__ unsigned short Vt[64 * RS];      // Vt[d][key]
    __shared__ unsigned short Ps[4][16 * RS];

    const int t    = threadIdx.x;
    const int wave = t >> 6;
    const int lane = t & 63;
    const int quad = lane >> 4;
    const int l16  = lane & 15;

    const int qt = blockIdx.x, h = blockIdx.y, b = blockIdx.z;
    const int bh = b * NH + h;
    const int q0 = qt * 64;
    const float scale2 = 0.125f * 1.4426950408889634f;  // HD^-0.5 * log2(e)

    const unsigned short* qbase  = qg + (size_t)bh * NN * HDIM + (size_t)q0 * HDIM;
    const unsigned short* kbase  = kg + (size_t)bh * NN * HDIM;
    const unsigned short* vtbase = vt + (size_t)bh * HDIM * NN;

    {
        const int row = t >> 2, col = (t & 3) * 16;
        const unsigned short* src = qbase + row * HDIM + col;
        *(bf16x8*)&Qs[row * RS + col]     = *(const bf16x8*)src;
        *(bf16x8*)&Qs[row * RS + col + 8] = *(const bf16x8*)(src + 8);
    }
    __syncthreads();

    bf16x8 aQ0 = *(const bf16x8*)&Qs[(wave * 16 + l16) * RS + quad * 8];
    bf16x8 aQ1 = *(const bf16x8*)&Qs[(wave * 16 + l16) * RS + quad * 8 + 32];

    const unsigned long long* bitrow =
        bitadj + (size_t)(q0 + wave * 16 + quad * 4) * 32;

    f32x4 O[4];
#pragma unroll
    for (int dt = 0; dt < 4; ++dt) O[dt] = (f32x4){0.f, 0.f, 0.f, 0.f};
    float m_r[4] = {-1e30f, -1e30f, -1e30f, -1e30f};
    float l_r[4] = {0.f, 0.f, 0.f, 0.f};

    for (int kt = 0; kt < NN / 64; ++kt) {
        const int k0 = kt * 64;
        __syncthreads();

        // ---- stage K (row-major keys x d) ----
        {
            const int row = t >> 2, col = (t & 3) * 16;
            const unsigned short* src = kbase + (size_t)(k0 + row) * HDIM + col;
            *(bf16x8*)&Ks[row * RS + col]     = *(const bf16x8*)src;
            *(bf16x8*)&Ks[row * RS + col + 8] = *(const bf16x8*)(src + 8);
        }
        // ---- stage V^T (d x keys) straight from global ----
        {
            const int row = t >> 2, col = (t & 3) * 16;
            const unsigned short* src = vtbase + (size_t)row * NN + k0 + col;
            *(bf16x8*)&Vt[row * RS + col]     = *(const bf16x8*)src;
            *(bf16x8*)&Vt[row * RS + col + 8] = *(const bf16x8*)(src + 8);
        }
        __syncthreads();

        // ---- QK^T ----
        f32x4 sc[4];
#pragma unroll
        for (int nt = 0; nt < 4; ++nt) {
            bf16x8 b0 = *(const bf16x8*)&Ks[(nt * 16 + l16) * RS + quad * 8];
            bf16x8 b1 = *(const bf16x8*)&Ks[(nt * 16 + l16) * RS + quad * 8 + 32];
            f32x4 c = (f32x4){0.f, 0.f, 0.f, 0.f};
            c = MFMA16(aQ0, b0, c);
            c = MFMA16(aQ1, b1, c);
            sc[nt] = c;
        }

        unsigned long long mreg[4];
#pragma unroll
        for (int r = 0; r < 4; ++r) mreg[r] = bitrow[r * 32 + kt];

        float s[4][4];
#pragma unroll
        for (int nt = 0; nt < 4; ++nt)
#pragma unroll
            for (int r = 0; r < 4; ++r) {
                const bool keep = (mreg[r] >> (nt * 16 + l16)) & 1ull;
                s[nt][r] = keep ? sc[nt][r] * scale2 : -1e30f;
            }

        float mnew[4], alpha[4];
#pragma unroll
        for (int r = 0; r < 4; ++r) {
            float rm = fmaxf(fmaxf(s[0][r], s[1][r]), fmaxf(s[2][r], s[3][r]));
            rm = fmaxf(rm, __shfl_xor(rm, 1));
            rm = fmaxf(rm, __shfl_xor(rm, 2));
            rm = fmaxf(rm, __shfl_xor(rm, 4));
            rm = fmaxf(rm, __shfl_xor(rm, 8));
            mnew[r]  = fmaxf(m_r[r], rm);
            alpha[r] = exp2f(m_r[r] - mnew[r]);
            m_r[r]   = mnew[r];
        }
        float rs[4] = {0.f, 0.f, 0.f, 0.f};
#pragma unroll
        for (int nt = 0; nt < 4; ++nt)
#pragma unroll
            for (int r = 0; r < 4; ++r) {
                const float p = exp2f(s[nt][r] - mnew[r]);
                s[nt][r] = p;
                rs[r] += p;
            }
#pragma unroll
        for (int r = 0; r < 4; ++r) {
            rs[r] += __shfl_xor(rs[r], 1);
            rs[r] += __shfl_xor(rs[r], 2);
            rs[r] += __shfl_xor(rs[r], 4);
            rs[r] += __shfl_xor(rs[r], 8);
            l_r[r] = l_r[r] * alpha[r] + rs[r];
        }

#pragma unroll
        for (int nt = 0; nt < 4; ++nt)
#pragma unroll
            for (int r = 0; r < 4; ++r)
                Ps[wave][(quad * 4 + r) * RS + nt * 16 + l16] = f2bf(s[nt][r]);

        bf16x8 aP0 = *(const bf16x8*)&Ps[wave][l16 * RS + quad * 8];
        bf16x8 aP1 = *(const bf16x8*)&Ps[wave][l16 * RS + quad * 8 + 32];
#pragma unroll
        for (int dt = 0; dt < 4; ++dt) {
#pragma unroll
            for (int r = 0; r < 4; ++r) O[dt][r] *= alpha[r];
            bf16x8 b0 = *(const bf16x8*)&Vt[(dt * 16 + l16) * RS + quad * 8];
            bf16x8 b1 = *(const bf16x8*)&Vt[(dt * 16 + l16) * RS + quad * 8 + 32];
            O[dt] = MFMA16(aP0, b0, O[dt]);
            O[dt] = MFMA16(aP1, b1, O[dt]);
        }
    }

    float inv[4];
#pragma unroll
    for (int r = 0; r < 4; ++r) inv[r] = 1.f / l_r[r];
#pragma unroll
    for (int dt = 0; dt < 4; ++dt)
#pragma unroll
        for (int r = 0; r < 4; ++r) {
            const int q = q0 + wave * 16 + quad * 4 + r;
            ao[((size_t)(b * NN + q)) * NOUT + h * HDIM + dt * 16 + l16] =
                f2bf(O[dt][r] * inv[r]);
        }
}

// ---------------------------------------------------------------------------
extern "C" void kernel_launch(void* const* d_in, const int* in_sizes, int n_in,
                              void* d_out, int out_size, void* d_ws, size_t ws_size,
                              hipStream_t stream)
{
    const float* x   = (const float*)d_in[0];
    const int*   adj = (const int*)  d_in[1];
    const float* Wq  = (const float*)d_in[2];
    const float* bq  = (const float*)d_in[3];
    const float* Wk  = (const float*)d_in[4];
    const float* bk  = (const float*)d_in[5];
    const float* Wv  = (const float*)d_in[6];
    const float* bv  = (const float*)d_in[7];
    const float* Wo  = (const float*)d_in[8];
    const float* bo  = (const float*)d_in[9];
    float* out = (float*)d_out;

    const size_t qkv_elems = (size_t)NB * NH * NN * HDIM;   // 4,194,304
    unsigned short* xb  = (unsigned short*)d_ws;
    unsigned short* q   = xb  + qkv_elems;
    unsigned short* kb  = q   + qkv_elems;
    unsigned short* vtb = kb  + qkv_elems;
    unsigned short* aob = vtb + qkv_elems;
    unsigned short* tWq = aob + qkv_elems;
    unsigned short* tWk = tWq + (size_t)DD * NOUT;
    unsigned short* tWv = tWk + (size_t)DD * NOUT;
    unsigned short* tWo = tWv + (size_t)DD * NOUT;
    unsigned long long* bits = (unsigned long long*)(tWo + (size_t)DD * NOUT);

    convx<<<dim3(4096), 256, 0, stream>>>(x, xb);
    transW<<<dim3(8, 8, 4), 256, 0, stream>>>(Wq, Wk, Wv, Wo, tWq, tWk, tWv, tWo);
    pack_adj<<<dim3(NN * 32 / 4), 256, 0, stream>>>(adj, bits);

    dim3 ggrid(NOUT / 128, (NB * NN) / 128);   // (4, 64)
    gemm_mfma<<<ggrid, 256, 0, stream>>>(xb, tWq, bq, q,   0);
    gemm_mfma<<<ggrid, 256, 0, stream>>>(xb, tWk, bk, kb,  0);
    gemm_mfma<<<ggrid, 256, 0, stream>>>(xb, tWv, bv, vtb, 1);

    attn_mfma<<<dim3(NN / 64, NH, NB), 256, 0, stream>>>(q, kb, vtb, bits, aob);

    gemm_mfma<<<ggrid, 256, 0, stream>>>(aob, tWo, bo, out, 2);
}

// Round 4
// 235.508 us; speedup vs baseline: 9.6424x; 1.3767x over previous
//
#include <hip/hip_runtime.h>
#include <math.h>

#define NB   4
#define NN   2048
#define DD   512
#define NOUT 512
#define NH   8
#define HDIM 64

typedef __attribute__((ext_vector_type(8))) short bf16x8;
typedef __attribute__((ext_vector_type(4))) float f32x4;
#define MFMA16(a, b, c) __builtin_amdgcn_mfma_f32_16x16x32_bf16(a, b, c, 0, 0, 0)

typedef const __attribute__((address_space(1))) unsigned int* gas_ptr;
typedef __attribute__((address_space(3))) unsigned int* las_ptr;

__device__ inline unsigned short f2bf(float f) {
    unsigned int u = __float_as_uint(f);
    u += 0x7fffu + ((u >> 16) & 1u);   // RNE
    return (unsigned short)(u >> 16);
}

// ---------------------------------------------------------------------------
// x fp32 [4M] -> bf16
// ---------------------------------------------------------------------------
__global__ __launch_bounds__(256) void convx(const float* __restrict__ x,
                                             unsigned short* __restrict__ xb)
{
    const int i = (blockIdx.x * 256 + threadIdx.x) * 4;
    float4 v = *(const float4*)(x + i);
    ushort4 u;
    u.x = f2bf(v.x); u.y = f2bf(v.y); u.z = f2bf(v.z); u.w = f2bf(v.w);
    *(ushort4*)(xb + i) = u;
}

// ---------------------------------------------------------------------------
// W [512 k][512 n] fp32 -> Wt [512 n][512 k] bf16   (4 matrices via blockIdx.z)
// ---------------------------------------------------------------------------
__global__ __launch_bounds__(256) void transW(
    const float* __restrict__ W0, const float* __restrict__ W1,
    const float* __restrict__ W2, const float* __restrict__ W3,
    unsigned short* __restrict__ T0, unsigned short* __restrict__ T1,
    unsigned short* __restrict__ T2, unsigned short* __restrict__ T3)
{
    __shared__ float tile[64][65];
    const float* W; unsigned short* T;
    switch (blockIdx.z) {
        case 0:  W = W0; T = T0; break;
        case 1:  W = W1; T = T1; break;
        case 2:  W = W2; T = T2; break;
        default: W = W3; T = T3; break;
    }
    const int t = threadIdx.x;
    const int k0 = blockIdx.x * 64, n0 = blockIdx.y * 64;
    const int r = t >> 6, c = t & 63;
#pragma unroll
    for (int rep = 0; rep < 16; ++rep) {
        const int row = rep * 4 + r;
        tile[row][c] = W[(size_t)(k0 + row) * NOUT + n0 + c];
    }
    __syncthreads();
#pragma unroll
    for (int rep = 0; rep < 16; ++rep) {
        const int row = rep * 4 + r;          // n index
        T[(size_t)(n0 + row) * DD + k0 + c] = f2bf(tile[c][row]);
    }
}

// ---------------------------------------------------------------------------
// adj -> bitmask [2048][32] u64
// ---------------------------------------------------------------------------
__global__ __launch_bounds__(256) void pack_adj(const int* __restrict__ adj,
                                                unsigned long long* __restrict__ bits)
{
    const int gw   = blockIdx.x * 4 + (threadIdx.x >> 6);
    const int lane = threadIdx.x & 63;
    const int row  = gw >> 5;
    const int word = gw & 31;
    const unsigned long long m = __ballot(adj[(size_t)row * NN + word * 64 + lane] != 0);
    if (lane == 0) bits[(size_t)row * 32 + word] = m;
}

// ---------------------------------------------------------------------------
// Fused QKV bf16 MFMA GEMM: [8192,512] @ Wt_cat[1536][512]^T
// 128x128 tile, BK=32, global_load_lds width 16, m97-style 2-barrier K-loop.
// seg 0 -> q [B,H,N,64] bf16; seg 1 -> k same; seg 2 -> v^T [B,H,64,N] bf16.
// ---------------------------------------------------------------------------
__global__ __launch_bounds__(256) void gemm_qkv(
    const unsigned short* __restrict__ A,
    const unsigned short* __restrict__ Wt,   // concatenated [1536][512]
    const float* __restrict__ bq, const float* __restrict__ bk,
    const float* __restrict__ bv,
    unsigned short* __restrict__ qo, unsigned short* __restrict__ ko,
    unsigned short* __restrict__ vto)
{
    __shared__ unsigned short As[4 * 128 * 8];   // [kc][m][8]
    __shared__ unsigned short Ws[4 * 128 * 8];   // [kc][n][8]

    const int t = threadIdx.x, wave = t >> 6, lane = t & 63;
    const int quad = lane >> 4, l16 = lane & 15;
    const int n0 = blockIdx.x * 128, m0 = blockIdx.y * 128;

    const int ca0 = wave * 2, ca1 = wave * 2 + 1;
    const int kcA0 = ca0 >> 1, hfA0 = ca0 & 1;
    const int kcA1 = ca1 >> 1, hfA1 = ca1 & 1;

    const unsigned short* gA0 = A  + (size_t)(m0 + hfA0 * 64 + lane) * DD + kcA0 * 8;
    const unsigned short* gA1 = A  + (size_t)(m0 + hfA1 * 64 + lane) * DD + kcA1 * 8;
    const unsigned short* gW0 = Wt + (size_t)(n0 + hfA0 * 64 + lane) * DD + kcA0 * 8;
    const unsigned short* gW1 = Wt + (size_t)(n0 + hfA1 * 64 + lane) * DD + kcA1 * 8;

    unsigned short* lA0 = As + (kcA0 * 128 + hfA0 * 64) * 8;
    unsigned short* lA1 = As + (kcA1 * 128 + hfA1 * 64) * 8;
    unsigned short* lW0 = Ws + (kcA0 * 128 + hfA0 * 64) * 8;
    unsigned short* lW1 = Ws + (kcA1 * 128 + hfA1 * 64) * 8;

    const int wm = (wave & 1) * 64, wn = (wave >> 1) * 64;

    f32x4 acc[4][4];
#pragma unroll
    for (int mt = 0; mt < 4; ++mt)
#pragma unroll
        for (int nt = 0; nt < 4; ++nt) acc[mt][nt] = (f32x4){0.f, 0.f, 0.f, 0.f};

    for (int kt = 0; kt < DD / 32; ++kt) {
        __syncthreads();
        __builtin_amdgcn_global_load_lds((gas_ptr)(gA0 + kt * 32), (las_ptr)lA0, 16, 0, 0);
        __builtin_amdgcn_global_load_lds((gas_ptr)(gA1 + kt * 32), (las_ptr)lA1, 16, 0, 0);
        __builtin_amdgcn_global_load_lds((gas_ptr)(gW0 + kt * 32), (las_ptr)lW0, 16, 0, 0);
        __builtin_amdgcn_global_load_lds((gas_ptr)(gW1 + kt * 32), (las_ptr)lW1, 16, 0, 0);
        __syncthreads();

        bf16x8 aF[4], bF[4];
#pragma unroll
        for (int mt = 0; mt < 4; ++mt)
            aF[mt] = *(const bf16x8*)&As[(quad * 128 + wm + mt * 16 + l16) * 8];
#pragma unroll
        for (int nt = 0; nt < 4; ++nt)
            bF[nt] = *(const bf16x8*)&Ws[(quad * 128 + wn + nt * 16 + l16) * 8];
#pragma unroll
        for (int mt = 0; mt < 4; ++mt)
#pragma unroll
            for (int nt = 0; nt < 4; ++nt)
                acc[mt][nt] = MFMA16(aF[mt], bF[nt], acc[mt][nt]);
    }

    const int seg   = n0 >> 9;           // 0:q 1:k 2:v
    const int nloc0 = n0 & 511;
    const float* bp = (seg == 0) ? bq : (seg == 1) ? bk : bv;
    unsigned short* dst3 = (seg == 0) ? qo : (seg == 1) ? ko : vto;

    float bias4[4];
#pragma unroll
    for (int nt = 0; nt < 4; ++nt) bias4[nt] = bp[nloc0 + wn + nt * 16 + l16];

#pragma unroll
    for (int mt = 0; mt < 4; ++mt) {
#pragma unroll
        for (int nt = 0; nt < 4; ++nt) {
            const int lcol = nloc0 + wn + nt * 16 + l16;
            const int h = lcol >> 6, d = lcol & 63;
#pragma unroll
            for (int r = 0; r < 4; ++r) {
                const int row = m0 + wm + mt * 16 + quad * 4 + r;
                const int bb = row >> 11, n = row & (NN - 1);
                const float val = acc[mt][nt][r] + bias4[nt];
                if (seg < 2)
                    dst3[((size_t)(bb * NH + h) * NN + n) * HDIM + d] = f2bf(val);
                else
                    dst3[((size_t)(bb * NH + h) * HDIM + d) * NN + n] = f2bf(val);
            }
        }
    }
}

// ---------------------------------------------------------------------------
// O-projection GEMM: out fp32 [8192,512] = aob @ Wo + bo
// ---------------------------------------------------------------------------
__global__ __launch_bounds__(256) void gemm_o(
    const unsigned short* __restrict__ A,
    const unsigned short* __restrict__ Wt,
    const float* __restrict__ bias,
    float* __restrict__ C)
{
    __shared__ unsigned short As[4 * 128 * 8];
    __shared__ unsigned short Ws[4 * 128 * 8];

    const int t = threadIdx.x, wave = t >> 6, lane = t & 63;
    const int quad = lane >> 4, l16 = lane & 15;
    const int n0 = blockIdx.x * 128, m0 = blockIdx.y * 128;

    const int ca0 = wave * 2, ca1 = wave * 2 + 1;
    const int kcA0 = ca0 >> 1, hfA0 = ca0 & 1;
    const int kcA1 = ca1 >> 1, hfA1 = ca1 & 1;

    const unsigned short* gA0 = A  + (size_t)(m0 + hfA0 * 64 + lane) * DD + kcA0 * 8;
    const unsigned short* gA1 = A  + (size_t)(m0 + hfA1 * 64 + lane) * DD + kcA1 * 8;
    const unsigned short* gW0 = Wt + (size_t)(n0 + hfA0 * 64 + lane) * DD + kcA0 * 8;
    const unsigned short* gW1 = Wt + (size_t)(n0 + hfA1 * 64 + lane) * DD + kcA1 * 8;

    unsigned short* lA0 = As + (kcA0 * 128 + hfA0 * 64) * 8;
    unsigned short* lA1 = As + (kcA1 * 128 + hfA1 * 64) * 8;
    unsigned short* lW0 = Ws + (kcA0 * 128 + hfA0 * 64) * 8;
    unsigned short* lW1 = Ws + (kcA1 * 128 + hfA1 * 64) * 8;

    const int wm = (wave & 1) * 64, wn = (wave >> 1) * 64;

    f32x4 acc[4][4];
#pragma unroll
    for (int mt = 0; mt < 4; ++mt)
#pragma unroll
        for (int nt = 0; nt < 4; ++nt) acc[mt][nt] = (f32x4){0.f, 0.f, 0.f, 0.f};

    for (int kt = 0; kt < DD / 32; ++kt) {
        __syncthreads();
        __builtin_amdgcn_global_load_lds((gas_ptr)(gA0 + kt * 32), (las_ptr)lA0, 16, 0, 0);
        __builtin_amdgcn_global_load_lds((gas_ptr)(gA1 + kt * 32), (las_ptr)lA1, 16, 0, 0);
        __builtin_amdgcn_global_load_lds((gas_ptr)(gW0 + kt * 32), (las_ptr)lW0, 16, 0, 0);
        __builtin_amdgcn_global_load_lds((gas_ptr)(gW1 + kt * 32), (las_ptr)lW1, 16, 0, 0);
        __syncthreads();

        bf16x8 aF[4], bF[4];
#pragma unroll
        for (int mt = 0; mt < 4; ++mt)
            aF[mt] = *(const bf16x8*)&As[(quad * 128 + wm + mt * 16 + l16) * 8];
#pragma unroll
        for (int nt = 0; nt < 4; ++nt)
            bF[nt] = *(const bf16x8*)&Ws[(quad * 128 + wn + nt * 16 + l16) * 8];
#pragma unroll
        for (int mt = 0; mt < 4; ++mt)
#pragma unroll
            for (int nt = 0; nt < 4; ++nt)
                acc[mt][nt] = MFMA16(aF[mt], bF[nt], acc[mt][nt]);
    }

    float bias4[4];
#pragma unroll
    for (int nt = 0; nt < 4; ++nt) bias4[nt] = bias[n0 + wn + nt * 16 + l16];

#pragma unroll
    for (int mt = 0; mt < 4; ++mt)
#pragma unroll
        for (int nt = 0; nt < 4; ++nt) {
            const int col = n0 + wn + nt * 16 + l16;
#pragma unroll
            for (int r = 0; r < 4; ++r) {
                const int row = m0 + wm + mt * 16 + quad * 4 + r;
                C[(size_t)row * NOUT + col] = acc[mt][nt][r] + bias4[nt];
            }
        }
}

// ---------------------------------------------------------------------------
// MFMA flash attention, fixed-max softmax (no cross-lane ops in main loop).
// Q/K/V^T staged via swizzled global_load_lds (XOR block swizzle in the
// GLOBAL source address; LDS stays linear -> frag reads are 2-way aliases).
// Row-sums accumulated by MFMA against an all-ones B fragment.
// ---------------------------------------------------------------------------
__global__ __launch_bounds__(256) void attn_mfma(
    const unsigned short* __restrict__ qg,
    const unsigned short* __restrict__ kg,
    const unsigned short* __restrict__ vt,
    const unsigned long long* __restrict__ bitadj,
    unsigned short* __restrict__ ao)
{
    __shared__ unsigned short Qs[64 * 64];
    __shared__ unsigned short Ks[64 * 64];
    __shared__ unsigned short Vt[64 * 64];      // Vt[d][key]
    __shared__ unsigned short Ps[4][16 * 72];   // per-wave P scratch (padded)

    const int t    = threadIdx.x;
    const int wave = t >> 6;
    const int lane = t & 63;
    const int quad = lane >> 4;
    const int l16  = lane & 15;

    const int qt = blockIdx.x, h = blockIdx.y, b = blockIdx.z;
    const int bh = b * NH + h;
    const int q0 = qt * 64;
    const float scale2 = 0.125f * 1.4426950408889634f;  // HD^-0.5 * log2(e)

    const unsigned short* qbase  = qg + (size_t)bh * NN * HDIM + (size_t)q0 * HDIM;
    const unsigned short* kbase  = kg + (size_t)bh * NN * HDIM;
    const unsigned short* vtbase = vt + (size_t)bh * HDIM * NN;

    // swizzled-DMA lane mapping: lane covers (row = 8*c_wave + lane/8,
    // global 16B-block dblk = (lane&7) ^ (row&7)); LDS placement is linear.
    const int drow = lane >> 3;              // row&7 within the wave's 8 rows
    const int dblk = (lane & 7) ^ drow;      // swizzled global block

    // frag-read addressing: row = X*16 + l16 -> row&7 == l16&7
    const int sw  = l16 & 7;
    const int bo0 = (quad ^ sw) * 8;         // chunk0 element offset in row
    const int bo1 = bo0 ^ 32;                // chunk1 ((quad^sw)^4)*8

    // ---- stage Q (swizzled DMA, 2 calls) ----
#pragma unroll
    for (int c = 0; c < 2; ++c) {
        const int r0 = c * 32 + wave * 8;
        __builtin_amdgcn_global_load_lds(
            (gas_ptr)(qbase + (size_t)(r0 + drow) * HDIM + dblk * 8),
            (las_ptr)(Qs + r0 * 64), 16, 0, 0);
    }
    __syncthreads();

    bf16x8 aQ0 = *(const bf16x8*)&Qs[(wave * 16 + l16) * 64 + bo0];
    bf16x8 aQ1 = *(const bf16x8*)&Qs[(wave * 16 + l16) * 64 + bo1];

    const unsigned long long* bitrow =
        bitadj + (size_t)(q0 + wave * 16 + quad * 4) * 32;

    bf16x8 onesb;
#pragma unroll
    for (int j = 0; j < 8; ++j) onesb[j] = (short)0x3F80;   // bf16 1.0

    f32x4 O[4];
#pragma unroll
    for (int dt = 0; dt < 4; ++dt) O[dt] = (f32x4){0.f, 0.f, 0.f, 0.f};
    f32x4 l_acc = (f32x4){0.f, 0.f, 0.f, 0.f};

    for (int kt = 0; kt < NN / 64; ++kt) {
        const int k0 = kt * 64;
        __syncthreads();   // prior tile's frag reads complete

        // ---- stage K and V^T (swizzled DMA) ----
#pragma unroll
        for (int c = 0; c < 2; ++c) {
            const int r0 = c * 32 + wave * 8;
            __builtin_amdgcn_global_load_lds(
                (gas_ptr)(kbase + (size_t)(k0 + r0 + drow) * HDIM + dblk * 8),
                (las_ptr)(Ks + r0 * 64), 16, 0, 0);
            __builtin_amdgcn_global_load_lds(
                (gas_ptr)(vtbase + (size_t)(r0 + drow) * NN + k0 + dblk * 8),
                (las_ptr)(Vt + r0 * 64), 16, 0, 0);
        }
        __syncthreads();   // drains vmcnt

        // ---- QK^T: 16 q x 64 k per wave ----
        f32x4 sc[4];
#pragma unroll
        for (int nt = 0; nt < 4; ++nt) {
            bf16x8 b0 = *(const bf16x8*)&Ks[(nt * 16 + l16) * 64 + bo0];
            bf16x8 b1 = *(const bf16x8*)&Ks[(nt * 16 + l16) * 64 + bo1];
            f32x4 c = (f32x4){0.f, 0.f, 0.f, 0.f};
            c = MFMA16(aQ0, b0, c);
            c = MFMA16(aQ1, b1, c);
            sc[nt] = c;
        }

        // ---- fixed-max softmax: p = exp2(s*scale2 - 8), masked -> 0 ----
        unsigned long long mreg[4];
#pragma unroll
        for (int r = 0; r < 4; ++r) mreg[r] = bitrow[r * 32 + kt];

#pragma unroll
        for (int nt = 0; nt < 4; ++nt)
#pragma unroll
            for (int r = 0; r < 4; ++r) {
                float p = exp2f(fmaf(sc[nt][r], scale2, -8.0f));
                const bool keep = (mreg[r] >> (nt * 16 + l16)) & 1ull;
                p = keep ? p : 0.f;
                Ps[wave][(quad * 4 + r) * 72 + nt * 16 + l16] = f2bf(p);
            }

        // ---- P A-frags; row-sum via MFMA(P, ones); PV ----
        bf16x8 aP0 = *(const bf16x8*)&Ps[wave][l16 * 72 + quad * 8];
        bf16x8 aP1 = *(const bf16x8*)&Ps[wave][l16 * 72 + quad * 8 + 32];
        l_acc = MFMA16(aP0, onesb, l_acc);
        l_acc = MFMA16(aP1, onesb, l_acc);
#pragma unroll
        for (int dt = 0; dt < 4; ++dt) {
            bf16x8 b0 = *(const bf16x8*)&Vt[(dt * 16 + l16) * 64 + bo0];
            bf16x8 b1 = *(const bf16x8*)&Vt[(dt * 16 + l16) * 64 + bo1];
            O[dt] = MFMA16(aP0, b0, O[dt]);
            O[dt] = MFMA16(aP1, b1, O[dt]);
        }
    }

    // ---- epilogue: normalize, write bf16 [B,N,OUT] ----
    float inv[4];
#pragma unroll
    for (int r = 0; r < 4; ++r) inv[r] = 1.f / l_acc[r];
#pragma unroll
    for (int dt = 0; dt < 4; ++dt)
#pragma unroll
        for (int r = 0; r < 4; ++r) {
            const int q = q0 + wave * 16 + quad * 4 + r;
            ao[((size_t)(b * NN + q)) * NOUT + h * HDIM + dt * 16 + l16] =
                f2bf(O[dt][r] * inv[r]);
        }
}

// ---------------------------------------------------------------------------
extern "C" void kernel_launch(void* const* d_in, const int* in_sizes, int n_in,
                              void* d_out, int out_size, void* d_ws, size_t ws_size,
                              hipStream_t stream)
{
    const float* x   = (const float*)d_in[0];
    const int*   adj = (const int*)  d_in[1];
    const float* Wq  = (const float*)d_in[2];
    const float* bq  = (const float*)d_in[3];
    const float* Wk  = (const float*)d_in[4];
    const float* bk  = (const float*)d_in[5];
    const float* Wv  = (const float*)d_in[6];
    const float* bv  = (const float*)d_in[7];
    const float* Wo  = (const float*)d_in[8];
    const float* bo  = (const float*)d_in[9];
    float* out = (float*)d_out;

    const size_t qkv_elems = (size_t)NB * NH * NN * HDIM;   // 4,194,304
    unsigned short* xb  = (unsigned short*)d_ws;
    unsigned short* q   = xb  + qkv_elems;
    unsigned short* kb  = q   + qkv_elems;
    unsigned short* vtb = kb  + qkv_elems;
    unsigned short* aob = vtb + qkv_elems;
    unsigned short* tWq = aob + qkv_elems;      // tWq/tWk/tWv contiguous = Wt_cat
    unsigned short* tWk = tWq + (size_t)DD * NOUT;
    unsigned short* tWv = tWk + (size_t)DD * NOUT;
    unsigned short* tWo = tWv + (size_t)DD * NOUT;
    unsigned long long* bits = (unsigned long long*)(tWo + (size_t)DD * NOUT);

    convx<<<dim3(4096), 256, 0, stream>>>(x, xb);
    transW<<<dim3(8, 8, 4), 256, 0, stream>>>(Wq, Wk, Wv, Wo, tWq, tWk, tWv, tWo);
    pack_adj<<<dim3(NN * 32 / 4), 256, 0, stream>>>(adj, bits);

    gemm_qkv<<<dim3(12, 64), 256, 0, stream>>>(xb, tWq, bq, bk, bv, q, kb, vtb);

    attn_mfma<<<dim3(NN / 64, NH, NB), 256, 0, stream>>>(q, kb, vtb, bits, aob);

    gemm_o<<<dim3(4, 64), 256, 0, stream>>>(aob, tWo, bo, out);
}

// Round 5
// 235.436 us; speedup vs baseline: 9.6454x; 1.0003x over previous
//
#include <hip/hip_runtime.h>
#include <math.h>

#define NB   4
#define NN   2048
#define DD   512
#define NOUT 512
#define NH   8
#define HDIM 64

typedef __attribute__((ext_vector_type(4))) short bf16x4;
typedef __attribute__((ext_vector_type(8))) short bf16x8;
typedef __attribute__((ext_vector_type(4))) float f32x4;
#define MFMA32(a, b, c)  __builtin_amdgcn_mfma_f32_16x16x32_bf16(a, b, c, 0, 0, 0)
#define MFMA16(a, b, c)  __builtin_amdgcn_mfma_f32_16x16x16bf16_1k(a, b, c, 0, 0, 0)

typedef const __attribute__((address_space(1))) unsigned int* gas_ptr;
typedef __attribute__((address_space(3))) unsigned int* las_ptr;

#define SCALE2 0.18033688f   /* 8^-1 * log2(e) */

__device__ inline unsigned short f2bf(float f) {
    unsigned int u = __float_as_uint(f);
    u += 0x7fffu + ((u >> 16) & 1u);   // RNE
    return (unsigned short)(u >> 16);
}

// pack two fp32 -> two bf16 (truncation) in ONE v_perm
__device__ inline unsigned int pack_trunc(float lo, float hi) {
    return __builtin_amdgcn_perm(__float_as_uint(hi), __float_as_uint(lo), 0x07060302u);
}

// ---------------------------------------------------------------------------
// prep: fused convx (x->bf16), transW (4 weights -> bf16 transposed),
// pack_adj (adj -> bit mask, TRANSPOSED layout bitsT[word][row]).
// grid = 2048 (conv) + 256 (transW) + 2048 (pack) = 4352 blocks
// ---------------------------------------------------------------------------
__global__ __launch_bounds__(256) void prep(
    const float* __restrict__ x, unsigned short* __restrict__ xb,
    const float* __restrict__ W0, const float* __restrict__ W1,
    const float* __restrict__ W2, const float* __restrict__ W3,
    unsigned short* __restrict__ T0, unsigned short* __restrict__ T1,
    unsigned short* __restrict__ T2, unsigned short* __restrict__ T3,
    const int* __restrict__ adj, unsigned long long* __restrict__ bitsT)
{
    const int blk = blockIdx.x;
    const int t   = threadIdx.x;

    if (blk < 2048) {                       // ---- convx: 8 floats/thread ----
        const int i = (blk * 256 + t) * 8;
        float4 a = *(const float4*)(x + i);
        float4 b = *(const float4*)(x + i + 4);
        ushort4 u0, u1;
        u0.x = f2bf(a.x); u0.y = f2bf(a.y); u0.z = f2bf(a.z); u0.w = f2bf(a.w);
        u1.x = f2bf(b.x); u1.y = f2bf(b.y); u1.z = f2bf(b.z); u1.w = f2bf(b.w);
        *(ushort4*)(xb + i)     = u0;
        *(ushort4*)(xb + i + 4) = u1;
        return;
    }
    if (blk < 2304) {                       // ---- transW ----
        __shared__ float tile[64][65];
        const int idx = blk - 2048;
        const int z = idx >> 6, rem = idx & 63;
        const float* W; unsigned short* T;
        switch (z) {
            case 0:  W = W0; T = T0; break;
            case 1:  W = W1; T = T1; break;
            case 2:  W = W2; T = T2; break;
            default: W = W3; T = T3; break;
        }
        const int k0 = (rem & 7) * 64, n0 = (rem >> 3) * 64;
        const int r = t >> 6, c = t & 63;
#pragma unroll
        for (int rep = 0; rep < 16; ++rep) {
            const int row = rep * 4 + r;
            tile[row][c] = W[(size_t)(k0 + row) * NOUT + n0 + c];
        }
        __syncthreads();
#pragma unroll
        for (int rep = 0; rep < 16; ++rep) {
            const int row = rep * 4 + r;          // n index
            T[(size_t)(n0 + row) * DD + k0 + c] = f2bf(tile[c][row]);
        }
        return;
    }
    // ---- pack_adj: bitsT[word*2048 + row], 8 words per wave ----
    {
        const int idx  = blk - 2304;
        const int wave = t >> 6, lane = t & 63;
        const int j    = idx * 4 + wave;          // 0..8191
        const int row  = j >> 2;
        const int wb   = (j & 3) * 8;
#pragma unroll
        for (int w = 0; w < 8; ++w) {
            const unsigned long long m =
                __ballot(adj[(size_t)row * NN + (wb + w) * 64 + lane] != 0);
            if (lane == 0) bitsT[(size_t)(wb + w) * NN + row] = m;
        }
    }
}

// ---------------------------------------------------------------------------
// GEMM helpers (shared by gemm_qkv / gemm_o): 128x128 tile, BK=32,
// double-buffered LDS, single barrier per K-step (prefetch overlaps compute).
// ---------------------------------------------------------------------------
#define G_SETUP()                                                              \
    const int t = threadIdx.x, wave = t >> 6, lane = t & 63;                   \
    const int quad = lane >> 4, l16 = lane & 15;                               \
    const int n0 = blockIdx.x * 128, m0 = blockIdx.y * 128;                    \
    const int ca0 = wave * 2, ca1 = wave * 2 + 1;                              \
    const int kcA0 = ca0 >> 1, hfA0 = ca0 & 1;                                 \
    const int kcA1 = ca1 >> 1, hfA1 = ca1 & 1;                                 \
    const unsigned short* gA0 = A  + (size_t)(m0 + hfA0 * 64 + lane) * DD + kcA0 * 8; \
    const unsigned short* gA1 = A  + (size_t)(m0 + hfA1 * 64 + lane) * DD + kcA1 * 8; \
    const unsigned short* gW0 = Wt + (size_t)(n0 + hfA0 * 64 + lane) * DD + kcA0 * 8; \
    const unsigned short* gW1 = Wt + (size_t)(n0 + hfA1 * 64 + lane) * DD + kcA1 * 8; \
    const int offA0 = (kcA0 * 128 + hfA0 * 64) * 8;                            \
    const int offA1 = (kcA1 * 128 + hfA1 * 64) * 8;                            \
    const int wm = (wave & 1) * 64, wn = (wave >> 1) * 64;

#define G_ISSUE(kt, AsB, WsB)                                                            \
    __builtin_amdgcn_global_load_lds((gas_ptr)(gA0 + (kt) * 32), (las_ptr)(AsB + offA0), 16, 0, 0); \
    __builtin_amdgcn_global_load_lds((gas_ptr)(gA1 + (kt) * 32), (las_ptr)(AsB + offA1), 16, 0, 0); \
    __builtin_amdgcn_global_load_lds((gas_ptr)(gW0 + (kt) * 32), (las_ptr)(WsB + offA0), 16, 0, 0); \
    __builtin_amdgcn_global_load_lds((gas_ptr)(gW1 + (kt) * 32), (las_ptr)(WsB + offA1), 16, 0, 0);

#define G_COMP(AsB, WsB) {                                                     \
    bf16x8 aF[4], bF[4];                                                       \
    _Pragma("unroll")                                                          \
    for (int mt = 0; mt < 4; ++mt)                                             \
        aF[mt] = *(const bf16x8*)&AsB[(quad * 128 + wm + mt * 16 + l16) * 8];  \
    _Pragma("unroll")                                                          \
    for (int nt = 0; nt < 4; ++nt)                                             \
        bF[nt] = *(const bf16x8*)&WsB[(quad * 128 + wn + nt * 16 + l16) * 8];  \
    _Pragma("unroll")                                                          \
    for (int mt = 0; mt < 4; ++mt)                                             \
        _Pragma("unroll")                                                      \
        for (int nt = 0; nt < 4; ++nt)                                         \
            acc[mt][nt] = MFMA32(aF[mt], bF[nt], acc[mt][nt]); }

#define G_LOOP()                                                               \
    f32x4 acc[4][4];                                                           \
    _Pragma("unroll")                                                          \
    for (int mt = 0; mt < 4; ++mt)                                             \
        _Pragma("unroll")                                                      \
        for (int nt = 0; nt < 4; ++nt) acc[mt][nt] = (f32x4){0.f, 0.f, 0.f, 0.f}; \
    G_ISSUE(0, As0, Ws0);                                                      \
    for (int kk = 0; kk < 8; ++kk) {                                           \
        __syncthreads();                                                       \
        G_ISSUE(2 * kk + 1, As1, Ws1);                                         \
        G_COMP(As0, Ws0);                                                      \
        __syncthreads();                                                       \
        if (kk < 7) { G_ISSUE(2 * kk + 2, As0, Ws0); }                         \
        G_COMP(As1, Ws1);                                                      \
    }

// ---------------------------------------------------------------------------
// Fused QKV GEMM: [8192,512] @ Wt_cat[1536][512]^T.
// seg0 -> q bf16 [B,H,N,64] PRE-SCALED by SCALE2; seg1 -> k; seg2 -> v^T.
// ---------------------------------------------------------------------------
__global__ __launch_bounds__(256) void gemm_qkv(
    const unsigned short* __restrict__ A,
    const unsigned short* __restrict__ Wt,
    const float* __restrict__ bq, const float* __restrict__ bk,
    const float* __restrict__ bv,
    unsigned short* __restrict__ qo, unsigned short* __restrict__ ko,
    unsigned short* __restrict__ vto)
{
    __shared__ unsigned short As0[4 * 128 * 8], Ws0[4 * 128 * 8];
    __shared__ unsigned short As1[4 * 128 * 8], Ws1[4 * 128 * 8];
    G_SETUP();
    G_LOOP();

    const int seg   = n0 >> 9;           // 0:q 1:k 2:v
    const int nloc0 = n0 & 511;
    const float* bp = (seg == 0) ? bq : (seg == 1) ? bk : bv;
    unsigned short* dst3 = (seg == 0) ? qo : (seg == 1) ? ko : vto;

    float bias4[4];
#pragma unroll
    for (int nt = 0; nt < 4; ++nt) bias4[nt] = bp[nloc0 + wn + nt * 16 + l16];

#pragma unroll
    for (int mt = 0; mt < 4; ++mt) {
#pragma unroll
        for (int nt = 0; nt < 4; ++nt) {
            const int lcol = nloc0 + wn + nt * 16 + l16;
            const int h = lcol >> 6, d = lcol & 63;
#pragma unroll
            for (int r = 0; r < 4; ++r) {
                const int row = m0 + wm + mt * 16 + quad * 4 + r;
                const int bb = row >> 11, n = row & (NN - 1);
                float val = acc[mt][nt][r] + bias4[nt];
                if (seg == 0) val *= SCALE2;
                if (seg < 2)
                    dst3[((size_t)(bb * NH + h) * NN + n) * HDIM + d] = f2bf(val);
                else
                    dst3[((size_t)(bb * NH + h) * HDIM + d) * NN + n] = f2bf(val);
            }
        }
    }
}

// ---------------------------------------------------------------------------
// O-projection GEMM: out fp32 [8192,512]
// ---------------------------------------------------------------------------
__global__ __launch_bounds__(256) void gemm_o(
    const unsigned short* __restrict__ A,
    const unsigned short* __restrict__ Wt,
    const float* __restrict__ bias,
    float* __restrict__ C)
{
    __shared__ unsigned short As0[4 * 128 * 8], Ws0[4 * 128 * 8];
    __shared__ unsigned short As1[4 * 128 * 8], Ws1[4 * 128 * 8];
    G_SETUP();
    G_LOOP();

    float bias4[4];
#pragma unroll
    for (int nt = 0; nt < 4; ++nt) bias4[nt] = bias[n0 + wn + nt * 16 + l16];

#pragma unroll
    for (int mt = 0; mt < 4; ++mt)
#pragma unroll
        for (int nt = 0; nt < 4; ++nt) {
            const int col = n0 + wn + nt * 16 + l16;
#pragma unroll
            for (int r = 0; r < 4; ++r) {
                const int row = m0 + wm + mt * 16 + quad * 4 + r;
                C[(size_t)row * NOUT + col] = acc[mt][nt][r] + bias4[nt];
            }
        }
}

// ---------------------------------------------------------------------------
// MFMA flash attention, transposed-score formulation.
// S^T = mfma32(A=K, B=Q): lane holds (key=quad*4+r, q=l16) -> P^T registers
// feed mfma16's B operand DIRECTLY (no LDS round trip, no shuffles).
// O^T[dt] = mfma16(A=V^T frag, B=Pt); l = mfma16(ones, Pt) -> one scalar/lane.
// K/V double-buffered, single barrier per tile (prefetch overlaps compute).
// ---------------------------------------------------------------------------
__global__ __launch_bounds__(256) void attn_mfma(
    const unsigned short* __restrict__ qg,
    const unsigned short* __restrict__ kg,
    const unsigned short* __restrict__ vt,
    const unsigned long long* __restrict__ bitT,   // [word][row]
    unsigned short* __restrict__ ao)
{
    __shared__ unsigned short Ka[64 * 64], Va[64 * 64];
    __shared__ unsigned short Kb[64 * 64], Vb[64 * 64];

    const int t    = threadIdx.x;
    const int wave = t >> 6;
    const int lane = t & 63;
    const int quad = lane >> 4;
    const int l16  = lane & 15;

    const int qt = blockIdx.x, h = blockIdx.y, b = blockIdx.z;
    const int bh = b * NH + h;
    const int q0 = qt * 64;

    const unsigned short* kbase  = kg + (size_t)bh * NN * HDIM;
    const unsigned short* vtbase = vt + (size_t)bh * HDIM * NN;

    // DMA swizzle (16B blocks): physical blk = logical blk ^ (row & 7)
    const int drow = lane >> 3;
    const int dblk = (lane & 7) ^ drow;

    // fragment-read swizzle offsets
    const int sw  = l16 & 7;
    const int bo0 = (quad ^ sw) * 8;         // K chunk0 (16B)
    const int bo1 = bo0 ^ 32;                // K chunk1
    int vofs[4];
#pragma unroll
    for (int c = 0; c < 4; ++c)
        vofs[c] = (((c * 2 + (quad >> 1)) ^ sw) * 8) + (quad & 1) * 4;  // V 8B frags

#define ATT_ISSUE(kt, Kd, Vd)                                                  \
    _Pragma("unroll")                                                          \
    for (int c = 0; c < 2; ++c) {                                              \
        const int r0 = c * 32 + wave * 8;                                      \
        __builtin_amdgcn_global_load_lds(                                      \
            (gas_ptr)(kbase + (size_t)((kt) * 64 + r0 + drow) * HDIM + dblk * 8), \
            (las_ptr)(Kd + r0 * 64), 16, 0, 0);                                \
        __builtin_amdgcn_global_load_lds(                                      \
            (gas_ptr)(vtbase + (size_t)(r0 + drow) * NN + (kt) * 64 + dblk * 8), \
            (las_ptr)(Vd + r0 * 64), 16, 0, 0);                                \
    }

    // Q B-fragments straight from global (row = this lane's query)
    const int myq = q0 + wave * 16 + l16;
    const unsigned short* qrow = qg + ((size_t)bh * NN + myq) * HDIM;
    const bf16x8 bQ0 = *(const bf16x8*)(qrow + quad * 8);
    const bf16x8 bQ1 = *(const bf16x8*)(qrow + quad * 8 + 32);

    bf16x4 ones4;
#pragma unroll
    for (int j = 0; j < 4; ++j) ones4[j] = (short)0x3F80;

    f32x4 O[4];
#pragma unroll
    for (int dt = 0; dt < 4; ++dt) O[dt] = (f32x4){0.f, 0.f, 0.f, 0.f};
    f32x4 lacc = (f32x4){0.f, 0.f, 0.f, 0.f};

    auto tile = [&](const unsigned short* Ks, const unsigned short* Vs, int kt) {
        const unsigned long long mreg = bitT[(size_t)kt * NN + myq];
        bf16x4 Pt[4];
#pragma unroll
        for (int nt = 0; nt < 4; ++nt) {
            bf16x8 aK0 = *(const bf16x8*)&Ks[(nt * 16 + l16) * 64 + bo0];
            bf16x8 aK1 = *(const bf16x8*)&Ks[(nt * 16 + l16) * 64 + bo1];
            f32x4 c = (f32x4){0.f, 0.f, 0.f, 0.f};
            c = MFMA32(aK0, bQ0, c);
            c = MFMA32(aK1, bQ1, c);
            const unsigned int mm = (unsigned int)(mreg >> (nt * 16 + quad * 4));
            float p0 = exp2f(c[0]); p0 = (mm & 1u)        ? p0 : 0.f;
            float p1 = exp2f(c[1]); p1 = ((mm >> 1) & 1u) ? p1 : 0.f;
            float p2 = exp2f(c[2]); p2 = ((mm >> 2) & 1u) ? p2 : 0.f;
            float p3 = exp2f(c[3]); p3 = ((mm >> 3) & 1u) ? p3 : 0.f;
            union { unsigned int u[2]; bf16x4 v; } cv;
            cv.u[0] = pack_trunc(p0, p1);
            cv.u[1] = pack_trunc(p2, p3);
            Pt[nt] = cv.v;
            lacc = MFMA16(ones4, Pt[nt], lacc);
        }
#pragma unroll
        for (int dt = 0; dt < 4; ++dt)
#pragma unroll
            for (int c4 = 0; c4 < 4; ++c4) {
                bf16x4 aV = *(const bf16x4*)&Vs[(dt * 16 + l16) * 64 + vofs[c4]];
                O[dt] = MFMA16(aV, Pt[c4], O[dt]);
            }
    };

    ATT_ISSUE(0, Ka, Va);
    for (int kk = 0; kk < 16; ++kk) {
        __syncthreads();
        ATT_ISSUE(2 * kk + 1, Kb, Vb);
        tile(Ka, Va, 2 * kk);
        __syncthreads();
        if (kk < 15) { ATT_ISSUE(2 * kk + 2, Ka, Va); }
        tile(Kb, Vb, 2 * kk + 1);
    }
    __syncthreads();   // all waves done reading K/V buffers

    // ---- epilogue: O^T -> LDS transpose (per-wave region) -> coalesced out
    const float inv = 1.f / lacc[0];
    unsigned short* Lo = (wave < 2) ? Ka : Kb;
    const int rloc = (wave & 1) * 16 + l16;           // row in region (= query)
#pragma unroll
    for (int dt = 0; dt < 4; ++dt) {
        const float v0 = O[dt][0] * inv, v1 = O[dt][1] * inv;
        const float v2 = O[dt][2] * inv, v3 = O[dt][3] * inv;
        *(unsigned int*)&Lo[rloc * 72 + dt * 16 + quad * 4]     = pack_trunc(v0, v1);
        *(unsigned int*)&Lo[rloc * 72 + dt * 16 + quad * 4 + 2] = pack_trunc(v2, v3);
    }
    // same-wave read-back, coalesced 16B stores
    const int rr = (wave & 1) * 16 + (lane >> 2);
    const int qq = q0 + wave * 16 + (lane >> 2);
#pragma unroll
    for (int i = 0; i < 2; ++i) {
        const int ch = (lane & 3) + 4 * i;
        bf16x8 val = *(const bf16x8*)&Lo[rr * 72 + ch * 8];
        *(bf16x8*)(ao + ((size_t)(b * NN + qq)) * NOUT + h * HDIM + ch * 8) = val;
    }
#undef ATT_ISSUE
}

// ---------------------------------------------------------------------------
extern "C" void kernel_launch(void* const* d_in, const int* in_sizes, int n_in,
                              void* d_out, int out_size, void* d_ws, size_t ws_size,
                              hipStream_t stream)
{
    const float* x   = (const float*)d_in[0];
    const int*   adj = (const int*)  d_in[1];
    const float* Wq  = (const float*)d_in[2];
    const float* bq  = (const float*)d_in[3];
    const float* Wk  = (const float*)d_in[4];
    const float* bk  = (const float*)d_in[5];
    const float* Wv  = (const float*)d_in[6];
    const float* bv  = (const float*)d_in[7];
    const float* Wo  = (const float*)d_in[8];
    const float* bo  = (const float*)d_in[9];
    float* out = (float*)d_out;

    const size_t qkv_elems = (size_t)NB * NH * NN * HDIM;   // 4,194,304
    unsigned short* xb  = (unsigned short*)d_ws;
    unsigned short* q   = xb  + qkv_elems;
    unsigned short* kb  = q   + qkv_elems;
    unsigned short* vtb = kb  + qkv_elems;
    unsigned short* aob = vtb + qkv_elems;
    unsigned short* tWq = aob + qkv_elems;      // tWq/tWk/tWv contiguous
    unsigned short* tWk = tWq + (size_t)DD * NOUT;
    unsigned short* tWv = tWk + (size_t)DD * NOUT;
    unsigned short* tWo = tWv + (size_t)DD * NOUT;
    unsigned long long* bitsT = (unsigned long long*)(tWo + (size_t)DD * NOUT);

    prep<<<dim3(4352), 256, 0, stream>>>(x, xb, Wq, Wk, Wv, Wo,
                                         tWq, tWk, tWv, tWo, adj, bitsT);

    gemm_qkv<<<dim3(12, 64), 256, 0, stream>>>(xb, tWq, bq, bk, bv, q, kb, vtb);

    attn_mfma<<<dim3(NN / 64, NH, NB), 256, 0, stream>>>(q, kb, vtb, bitsT, aob);

    gemm_o<<<dim3(4, 64), 256, 0, stream>>>(aob, tWo, bo, out);
}